// Round 19
// baseline (235.860 us; speedup 1.0000x reference)
//
#include <hip/hip_runtime.h>
#include <hip/hip_fp16.h>

// Simple GNN: h = X@W_in+b; 4x { agg = segmean(w*h[src], dst); h += lrelu(agg@W_l+b_l) }
// out = (h@W_out+b_out, h)
// Round 19: revert to r16's known-good 256-thread fused layer (r17/r18's 512-thread
//           variant had structural corruption). New: DESCENDING-degree permutation so
//           long-pole blocks are scheduled first (shrinks straggler tail). Defensive
//           clamps kept.

#define N_NODES 50000
#define N_EDGES 625000
#define IN_F 64
#define INT_F 128
#define OUT_F 32
#define DEPTH 4
#define NEG_SLOPE 0.01f

#define SCAN_BLOCKS 196            // 196*256 = 50176 >= N_NODES
#define DMAX 64                    // degree buckets 0..63 (clamped)
#define TS_N (DMAX * SCAN_BLOCKS)  // 12544 transposed-hist elements
#define TS_BLOCKS ((TS_N + 255) / 256)  // 49

typedef _Float16 half8 __attribute__((ext_vector_type(8)));
typedef float floatx4 __attribute__((ext_vector_type(4)));

// ---- in-degree + slot ----
__global__ void deg_slot_kernel(const int2* __restrict__ ei, int* __restrict__ deg,
                                int* __restrict__ slot) {
    int i = blockIdx.x * blockDim.x + threadIdx.x;
    if (i < N_EDGES) slot[i] = atomicAdd(&deg[ei[i].y], 1);
}

// ---- row_ptr scan stage 1 ----
__global__ void scan1_kernel(const int* __restrict__ deg, int* __restrict__ partial) {
    int node = blockIdx.x * 256 + threadIdx.x;
    int v = (node < N_NODES) ? deg[node] : 0;
    __shared__ int sd[256];
    sd[threadIdx.x] = v;
    __syncthreads();
    for (int off = 128; off > 0; off >>= 1) {
        if (threadIdx.x < off) sd[threadIdx.x] += sd[threadIdx.x + off];
        __syncthreads();
    }
    if (threadIdx.x == 0) partial[blockIdx.x] = sd[0];
}

// ---- row_ptr scan stage 2 ----
__global__ void scan2_kernel(const int* __restrict__ partial, int* __restrict__ base,
                             int* __restrict__ row_ptr) {
    __shared__ int ps[256];
    int t = threadIdx.x;
    int v = (t < SCAN_BLOCKS) ? partial[t] : 0;
    ps[t] = v;
    __syncthreads();
    for (int off = 1; off < 256; off <<= 1) {
        int add = (t >= off) ? ps[t - off] : 0;
        __syncthreads();
        ps[t] += add;
        __syncthreads();
    }
    if (t < SCAN_BLOCKS) base[t] = ps[t] - v;
    if (t == SCAN_BLOCKS - 1) row_ptr[N_NODES] = ps[t];
}

// ---- row_ptr scan stage 3 ----
__global__ void scan3_kernel(const int* __restrict__ deg, const int* __restrict__ base,
                             int* __restrict__ row_ptr) {
    int node = blockIdx.x * 256 + threadIdx.x;
    int t = threadIdx.x;
    int d = (node < N_NODES) ? deg[node] : 0;
    __shared__ int ps[256];
    ps[t] = d;
    __syncthreads();
    for (int off = 1; off < 256; off <<= 1) {
        int add = (t >= off) ? ps[t - off] : 0;
        __syncthreads();
        ps[t] += add;
        __syncthreads();
    }
    if (node < N_NODES) row_ptr[node] = base[blockIdx.x] + ps[t] - d;
}

// ---- per-block LDS degree histogram (TRANSPOSED out) + in-block rank ----
__global__ void bhist_kernel(const int* __restrict__ deg, int* __restrict__ bhistT,
                             int* __restrict__ rank) {
    __shared__ int lh[DMAX];
    const int t = threadIdx.x;
    if (t < DMAX) lh[t] = 0;
    __syncthreads();
    int n = blockIdx.x * 256 + t;
    if (n < N_NODES) {
        int b = min(deg[n], DMAX - 1);
        rank[n] = atomicAdd(&lh[b], 1);  // LDS atomic
    }
    __syncthreads();
    if (t < DMAX) bhistT[t * SCAN_BLOCKS + blockIdx.x] = lh[t];  // bucket-major
}

// ---- generic 3-stage exclusive scan over TS_N ints (bucket-major hist) ----
__global__ void gscan1_kernel(const int* __restrict__ in, int* __restrict__ partial) {
    int i = blockIdx.x * 256 + threadIdx.x;
    int v = (i < TS_N) ? in[i] : 0;
    __shared__ int sd[256];
    sd[threadIdx.x] = v;
    __syncthreads();
    for (int off = 128; off > 0; off >>= 1) {
        if (threadIdx.x < off) sd[threadIdx.x] += sd[threadIdx.x + off];
        __syncthreads();
    }
    if (threadIdx.x == 0) partial[blockIdx.x] = sd[0];
}
__global__ void gscan2_kernel(const int* __restrict__ partial, int* __restrict__ base) {
    __shared__ int ps[256];
    int t = threadIdx.x;
    int v = (t < TS_BLOCKS) ? partial[t] : 0;
    ps[t] = v;
    __syncthreads();
    for (int off = 1; off < 256; off <<= 1) {
        int add = (t >= off) ? ps[t - off] : 0;
        __syncthreads();
        ps[t] += add;
        __syncthreads();
    }
    if (t < TS_BLOCKS) base[t] = ps[t] - v;
}
__global__ void gscan3_kernel(const int* __restrict__ in, const int* __restrict__ base,
                              int* __restrict__ out) {
    int i = blockIdx.x * 256 + threadIdx.x;
    int t = threadIdx.x;
    int v = (i < TS_N) ? in[i] : 0;
    __shared__ int ps[256];
    ps[t] = v;
    __syncthreads();
    for (int off = 1; off < 256; off <<= 1) {
        int add = (t >= off) ? ps[t - off] : 0;
        __syncthreads();
        ps[t] += add;
        __syncthreads();
    }
    if (i < TS_N) out[i] = base[blockIdx.x] + ps[t] - v;  // exclusive
}

// ---- scatter nodes into DESCENDING-degree permutation (no global atomics) ----
__global__ void perm2_kernel(const int* __restrict__ deg, const int* __restrict__ rank,
                             const int* __restrict__ bbase2T, int* __restrict__ perm) {
    int n = blockIdx.x * 256 + threadIdx.x;
    if (n < N_NODES) {
        int b = min(deg[n], DMAX - 1);
        int pos = bbase2T[b * SCAN_BLOCKS + blockIdx.x] + rank[n];
        pos = N_NODES - 1 - pos;  // reverse: highest-degree nodes land in block 0
        if (pos >= 0 && pos < N_NODES) perm[pos] = n;
    }
}

// ---- non-atomic scatter into packed CSR: csru[pos] = (fp16(w)<<16) | src ----
__global__ void build_csr_kernel(const int2* __restrict__ ei, const float* __restrict__ ew,
                                 const int* __restrict__ slot, const int* __restrict__ row_ptr,
                                 unsigned int* __restrict__ csru) {
    int e = blockIdx.x * blockDim.x + threadIdx.x;
    if (e >= N_EDGES) return;
    int2 sd = ei[e];
    int pos = row_ptr[sd.y] + slot[e];
    unsigned short wh = __half_as_ushort(__float2half(ew[e]));
    if (pos >= 0 && pos < N_EDGES)
        csru[pos] = (unsigned int)sd.x | ((unsigned int)wh << 16);  // src < 65536
}

// ---- fp16 transposed weights: WT16 (4 layers) then WTO16 (out proj) in one launch ----
__global__ void prep_w_kernel(const float* __restrict__ W_layers, const float* __restrict__ W_out,
                              _Float16* __restrict__ WT16, _Float16* __restrict__ WTO16) {
    int idx = blockIdx.x * 256 + threadIdx.x;
    if (idx < DEPTH * INT_F * INT_F) {
        int l = idx >> 14;
        int rem = idx & 16383;
        int n = rem >> 7;
        int k = rem & 127;
        WT16[idx] = (_Float16)W_layers[(size_t)l * 16384 + (size_t)k * 128 + n];
    } else {
        int j = idx - DEPTH * INT_F * INT_F;  // < 4096
        int n = j >> 7;
        int k = j & 127;
        WTO16[j] = (_Float16)W_out[(size_t)k * OUT_F + n];
    }
}

// ---- h16 = fp16(X @ W_in + b_in)  (16 nodes per 256-thread block) ----
__global__ void gemm_in_kernel(const float* __restrict__ X, const float* __restrict__ W,
                               const float* __restrict__ b, __half* __restrict__ h16) {
    __shared__ float xs[16][IN_F];
    const int base = blockIdx.x * 16;
    const int t = threadIdx.x;
    ((float4*)xs)[t] = ((const float4*)(X + (size_t)base * IN_F))[t];
    __syncthreads();
    const int f = t & (INT_F - 1);
    const int rg = t >> 7;
    float acc[8];
    const float bv = b[f];
#pragma unroll
    for (int j = 0; j < 8; ++j) acc[j] = bv;
#pragma unroll 4
    for (int k = 0; k < IN_F; ++k) {
        float w = W[k * INT_F + f];
#pragma unroll
        for (int j = 0; j < 8; ++j) acc[j] += xs[rg * 8 + j][k] * w;
    }
#pragma unroll
    for (int j = 0; j < 8; ++j)
        h16[(size_t)(base + rg * 8 + j) * INT_F + f] = __float2half(acc[j]);
}

// ---- fused layer (perm order): 256 thr = 4 waves = 16 nodes ----
template <bool LAST>
__global__ __launch_bounds__(256) void fused_layer_kernel(
    const int* __restrict__ row_ptr, const unsigned int* __restrict__ csru,
    const int* __restrict__ perm, const __half* h16_in, const _Float16* __restrict__ WT16,
    const float* __restrict__ b, __half* __restrict__ h16_out,
    const _Float16* __restrict__ WTO16, const float* __restrict__ b_out,
    float* __restrict__ h_fp32_out, float* __restrict__ out1) {
    __shared__ _Float16 as[16 * 136];  // 16 rows x 272B (128 halves + 8 pad)
    __shared__ int pnodes[16];
    const int t = threadIdx.x;         // 0..255
    const int row0 = blockIdx.x * 16;  // 3125 * 16 == 50000, exact

    if (t < 16) {
        int n = perm[row0 + t];
        pnodes[t] = (n >= 0 && n < N_NODES) ? n : 0;  // clamp: fault -> wrong answer
    }
    __syncthreads();

    // ---- phase 1: gather. 16 lanes/node; lane covers 8 features (1 uint4). ----
    const int nl = t >> 4;  // local node 0..15
    const int sl = t & 15;  // feature sixteenth
    const int node = pnodes[nl];
    const uint4* h16q = (const uint4*)h16_in;

    int s = row_ptr[node], e = row_ptr[node + 1];
    s = max(0, min(s, N_EDGES));   // clamp: fault -> wrong answer
    e = max(s, min(e, N_EDGES));
    __half2 acc2[4];
    const __half2 zero2 = __floats2half2_rn(0.f, 0.f);
#pragma unroll
    for (int q = 0; q < 4; ++q) acc2[q] = zero2;

    int i = s;
    for (; i + 3 < e; i += 4) {  // 4 independent row loads in flight
        unsigned int u0 = csru[i], u1 = csru[i + 1], u2 = csru[i + 2], u3 = csru[i + 3];
        uint4 r0 = h16q[(size_t)(u0 & 0xFFFFu) * 16 + sl];
        uint4 r1 = h16q[(size_t)(u1 & 0xFFFFu) * 16 + sl];
        uint4 r2 = h16q[(size_t)(u2 & 0xFFFFu) * 16 + sl];
        uint4 r3 = h16q[(size_t)(u3 & 0xFFFFu) * 16 + sl];
        __half2 w0 = __half2half2(__ushort_as_half((unsigned short)(u0 >> 16)));
        __half2 w1 = __half2half2(__ushort_as_half((unsigned short)(u1 >> 16)));
        __half2 w2 = __half2half2(__ushort_as_half((unsigned short)(u2 >> 16)));
        __half2 w3 = __half2half2(__ushort_as_half((unsigned short)(u3 >> 16)));
        const __half2* p0 = (const __half2*)&r0;
        const __half2* p1 = (const __half2*)&r1;
        const __half2* p2 = (const __half2*)&r2;
        const __half2* p3 = (const __half2*)&r3;
#pragma unroll
        for (int q = 0; q < 4; ++q) {
            acc2[q] = __hfma2(w0, p0[q], acc2[q]);
            acc2[q] = __hfma2(w1, p1[q], acc2[q]);
            acc2[q] = __hfma2(w2, p2[q], acc2[q]);
            acc2[q] = __hfma2(w3, p3[q], acc2[q]);
        }
    }
    for (; i < e; ++i) {
        unsigned int u0 = csru[i];
        uint4 r0 = h16q[(size_t)(u0 & 0xFFFFu) * 16 + sl];
        __half2 w0 = __half2half2(__ushort_as_half((unsigned short)(u0 >> 16)));
        const __half2* p0 = (const __half2*)&r0;
#pragma unroll
        for (int q = 0; q < 4; ++q) acc2[q] = __hfma2(w0, p0[q], acc2[q]);
    }
    const float inv = 1.0f / fmaxf((float)(e - s), 1.0f);

    // mean in fp32, stage to LDS
    {
        uint4 o;
        unsigned int* op = &o.x;
#pragma unroll
        for (int q = 0; q < 4; ++q) {
            float2 f = __half22float2(acc2[q]);
            __half2 hv = __floats2half2_rn(f.x * inv, f.y * inv);
            op[q] = *(const unsigned int*)&hv;
        }
        *(uint4*)(as + nl * 136 + sl * 8) = o;
    }
    __syncthreads();

    // ---- phase 2: MFMA. wave wv computes col-tiles [wv*2, wv*2+2). ----
    const int wv = t >> 6;
    const int lane = t & 63;
    const int r = lane & 15;
    const int ksel = lane >> 4;

    half8 afr[4];
#pragma unroll
    for (int ks = 0; ks < 4; ++ks)
        afr[ks] = *(const half8*)(as + r * 136 + ks * 32 + ksel * 8);

    floatx4 accd[2];
#pragma unroll
    for (int c4 = 0; c4 < 2; ++c4) accd[c4] = (floatx4){0.f, 0.f, 0.f, 0.f};

#pragma unroll
    for (int c4 = 0; c4 < 2; ++c4) {
        const int ct = wv * 2 + c4;
        const _Float16* wbase = WT16 + (size_t)(ct * 16 + r) * INT_F + ksel * 8;
        half8 b0 = *(const half8*)(wbase + 0);
        half8 b1 = *(const half8*)(wbase + 32);
        half8 b2 = *(const half8*)(wbase + 64);
        half8 b3 = *(const half8*)(wbase + 96);
        accd[c4] = __builtin_amdgcn_mfma_f32_16x16x32_f16(afr[0], b0, accd[c4], 0, 0, 0);
        accd[c4] = __builtin_amdgcn_mfma_f32_16x16x32_f16(afr[1], b1, accd[c4], 0, 0, 0);
        accd[c4] = __builtin_amdgcn_mfma_f32_16x16x32_f16(afr[2], b2, accd[c4], 0, 0, 0);
        accd[c4] = __builtin_amdgcn_mfma_f32_16x16x32_f16(afr[3], b3, accd[c4], 0, 0, 0);
    }

    // ---- phase 3a: bias + lrelu, write activation back to LDS (fp16) ----
    __syncthreads();
#pragma unroll
    for (int c4 = 0; c4 < 2; ++c4) {
        const int ct = wv * 2 + c4;
        const int col = ct * 16 + r;
        const float bias = b[col];
#pragma unroll
        for (int reg = 0; reg < 4; ++reg) {
            const int rowl = ksel * 4 + reg;
            float z = accd[c4][reg] + bias;
            float a = (z >= 0.f) ? z : NEG_SLOPE * z;
            as[rowl * 136 + col] = (_Float16)a;
        }
    }
    __syncthreads();

    // ---- phase 3b: coalesced residual + full-line stores; LAST refills LDS with h_final ----
    {
        const int rowl = t >> 4;
        const int part = t & 15;
        const int row = pnodes[rowl];
        uint4 av = *(const uint4*)(as + rowl * 136 + part * 8);
        uint4 hv = h16q[(size_t)row * 16 + part];
        const __half2* ap = (const __half2*)&av;
        const __half2* hp = (const __half2*)&hv;
        uint4 o;
        unsigned int* op = &o.x;
        float nh[8];
#pragma unroll
        for (int q = 0; q < 4; ++q) {
            float2 fa = __half22float2(ap[q]);
            float2 fh = __half22float2(hp[q]);
            nh[2 * q + 0] = fh.x + fa.x;
            nh[2 * q + 1] = fh.y + fa.y;
            __half2 hv2 = __floats2half2_rn(nh[2 * q], nh[2 * q + 1]);
            op[q] = *(const unsigned int*)&hv2;
        }
        ((uint4*)h16_out)[(size_t)row * 16 + part] = o;
        if (LAST) {
            float4* f4 = (float4*)(h_fp32_out + (size_t)row * INT_F + part * 8);
            f4[0] = make_float4(nh[0], nh[1], nh[2], nh[3]);
            f4[1] = make_float4(nh[4], nh[5], nh[6], nh[7]);
            *(uint4*)(as + rowl * 136 + part * 8) = o;  // h_final for out-proj
        }
    }

    // ---- phase 4 (LAST only): out = h_final @ W_out + b_out via MFMA on waves 0-1 ----
    if (LAST) {
        __syncthreads();
        if (wv < 2) {
            half8 ofr[4];
#pragma unroll
            for (int ks = 0; ks < 4; ++ks)
                ofr[ks] = *(const half8*)(as + r * 136 + ks * 32 + ksel * 8);
            floatx4 acco = (floatx4){0.f, 0.f, 0.f, 0.f};
            const _Float16* wbase = WTO16 + (size_t)(wv * 16 + r) * INT_F + ksel * 8;
            half8 b0 = *(const half8*)(wbase + 0);
            half8 b1 = *(const half8*)(wbase + 32);
            half8 b2 = *(const half8*)(wbase + 64);
            half8 b3 = *(const half8*)(wbase + 96);
            acco = __builtin_amdgcn_mfma_f32_16x16x32_f16(ofr[0], b0, acco, 0, 0, 0);
            acco = __builtin_amdgcn_mfma_f32_16x16x32_f16(ofr[1], b1, acco, 0, 0, 0);
            acco = __builtin_amdgcn_mfma_f32_16x16x32_f16(ofr[2], b2, acco, 0, 0, 0);
            acco = __builtin_amdgcn_mfma_f32_16x16x32_f16(ofr[3], b3, acco, 0, 0, 0);
            const int col = wv * 16 + r;
            const float bias = b_out[col];
#pragma unroll
            for (int reg = 0; reg < 4; ++reg) {
                const int rowl = ksel * 4 + reg;
                const int row = pnodes[rowl];
                out1[(size_t)row * OUT_F + col] = acco[reg] + bias;
            }
        }
    }
}

extern "C" void kernel_launch(void* const* d_in, const int* in_sizes, int n_in,
                              void* d_out, int out_size, void* d_ws, size_t ws_size,
                              hipStream_t stream) {
    const float* X        = (const float*)d_in[0];
    const int2*  ei       = (const int2*)d_in[1];
    const float* ew       = (const float*)d_in[2];
    const float* W_in     = (const float*)d_in[3];
    const float* b_in     = (const float*)d_in[4];
    const float* W_layers = (const float*)d_in[5];
    const float* b_layers = (const float*)d_in[6];
    const float* W_out    = (const float*)d_in[7];
    const float* b_out    = (const float*)d_in[8];

    float* out1 = (float*)d_out;
    float* hf32 = out1 + (size_t)N_NODES * OUT_F;  // fp32 h output (written by last layer)

    // workspace layout (~32 MB); 16B alignment maintained
    char* ws = (char*)d_ws;
    __half*   h16A  = (__half*)ws;    ws += (size_t)N_NODES * INT_F * 2;        // 12.8 MB
    __half*   h16B  = (__half*)ws;    ws += (size_t)N_NODES * INT_F * 2;        // 12.8 MB
    _Float16* WT16  = (_Float16*)ws;  ws += (size_t)DEPTH * INT_F * INT_F * 2;  // 128 KB
    _Float16* WTO16 = (_Float16*)ws;  ws += (size_t)OUT_F * INT_F * 2;          // 8 KB
    unsigned int* csru = (unsigned int*)ws;  ws += (size_t)N_EDGES * 4;         // 2.5 MB
    int*  slot    = (int*)ws;   ws += (size_t)N_EDGES * 4;                      // 2.5 MB
    int*  row_ptr = (int*)ws;   ws += (size_t)(N_NODES + 1) * 4;
    int*  deg     = (int*)ws;   ws += (size_t)N_NODES * 4;
    int*  rank    = (int*)ws;   ws += (size_t)N_NODES * 4;
    int*  perm    = (int*)ws;   ws += (size_t)N_NODES * 4;
    int*  bhistT  = (int*)ws;   ws += (size_t)TS_N * 4;                         // 50 KB
    int*  bbase2T = (int*)ws;   ws += (size_t)TS_N * 4;                         // 50 KB
    int*  partial = (int*)ws;   ws += (size_t)SCAN_BLOCKS * 4;
    int*  bbase   = (int*)ws;   ws += (size_t)SCAN_BLOCKS * 4;
    int*  tpart   = (int*)ws;   ws += (size_t)TS_BLOCKS * 4;
    int*  tbase   = (int*)ws;   ws += (size_t)TS_BLOCKS * 4;

    // ---- build CSR + degree-sorted perm + fp16 weights (once per call) ----
    (void)hipMemsetAsync(deg, 0, (size_t)N_NODES * 4, stream);
    deg_slot_kernel<<<(N_EDGES + 255) / 256, 256, 0, stream>>>(ei, deg, slot);
    scan1_kernel<<<SCAN_BLOCKS, 256, 0, stream>>>(deg, partial);
    scan2_kernel<<<1, 256, 0, stream>>>(partial, bbase, row_ptr);
    scan3_kernel<<<SCAN_BLOCKS, 256, 0, stream>>>(deg, bbase, row_ptr);
    bhist_kernel<<<SCAN_BLOCKS, 256, 0, stream>>>(deg, bhistT, rank);
    gscan1_kernel<<<TS_BLOCKS, 256, 0, stream>>>(bhistT, tpart);
    gscan2_kernel<<<1, 256, 0, stream>>>(tpart, tbase);
    gscan3_kernel<<<TS_BLOCKS, 256, 0, stream>>>(bhistT, tbase, bbase2T);
    perm2_kernel<<<SCAN_BLOCKS, 256, 0, stream>>>(deg, rank, bbase2T, perm);
    build_csr_kernel<<<(N_EDGES + 255) / 256, 256, 0, stream>>>(ei, ew, slot, row_ptr, csru);
    prep_w_kernel<<<(DEPTH * INT_F * INT_F + OUT_F * INT_F) / 256, 256, 0, stream>>>(
        W_layers, W_out, WT16, WTO16);

    // ---- input projection (fp16 h) ----
    gemm_in_kernel<<<N_NODES / 16, 256, 0, stream>>>(X, W_in, b_in, h16A);

    // ---- fused layers: ping-pong; last layer writes fp32 h + out1 ----
    __half* hin = h16A;
    __half* hout = h16B;
    for (int i = 0; i < DEPTH - 1; ++i) {
        fused_layer_kernel<false><<<N_NODES / 16, 256, 0, stream>>>(
            row_ptr, csru, perm, hin, WT16 + (size_t)i * INT_F * INT_F,
            b_layers + (size_t)i * INT_F, hout, WTO16, b_out, nullptr, nullptr);
        __half* tmp = hin; hin = hout; hout = tmp;
    }
    fused_layer_kernel<true><<<N_NODES / 16, 256, 0, stream>>>(
        row_ptr, csru, perm, hin, WT16 + (size_t)(DEPTH - 1) * INT_F * INT_F,
        b_layers + (size_t)(DEPTH - 1) * INT_F, hout, WTO16, b_out, hf32, out1);
}

// Round 20
// 226.128 us; speedup vs baseline: 1.0430x; 1.0430x over previous
//
#include <hip/hip_runtime.h>
#include <hip/hip_fp16.h>

// Simple GNN: h = X@W_in+b; 4x { agg = segmean(w*h[src], dst); h += lrelu(agg@W_l+b_l) }
// out = (h@W_out+b_out, h)
// Round 20: ascending perm restored (r19's descending was -9us), LAST layer no longer
//           writes the dead h16_out buffer (12.8MB saved). Clamps kept.

#define N_NODES 50000
#define N_EDGES 625000
#define IN_F 64
#define INT_F 128
#define OUT_F 32
#define DEPTH 4
#define NEG_SLOPE 0.01f

#define SCAN_BLOCKS 196            // 196*256 = 50176 >= N_NODES
#define DMAX 64                    // degree buckets 0..63 (clamped)
#define TS_N (DMAX * SCAN_BLOCKS)  // 12544 transposed-hist elements
#define TS_BLOCKS ((TS_N + 255) / 256)  // 49

typedef _Float16 half8 __attribute__((ext_vector_type(8)));
typedef float floatx4 __attribute__((ext_vector_type(4)));

// ---- in-degree + slot ----
__global__ void deg_slot_kernel(const int2* __restrict__ ei, int* __restrict__ deg,
                                int* __restrict__ slot) {
    int i = blockIdx.x * blockDim.x + threadIdx.x;
    if (i < N_EDGES) slot[i] = atomicAdd(&deg[ei[i].y], 1);
}

// ---- row_ptr scan stage 1 ----
__global__ void scan1_kernel(const int* __restrict__ deg, int* __restrict__ partial) {
    int node = blockIdx.x * 256 + threadIdx.x;
    int v = (node < N_NODES) ? deg[node] : 0;
    __shared__ int sd[256];
    sd[threadIdx.x] = v;
    __syncthreads();
    for (int off = 128; off > 0; off >>= 1) {
        if (threadIdx.x < off) sd[threadIdx.x] += sd[threadIdx.x + off];
        __syncthreads();
    }
    if (threadIdx.x == 0) partial[blockIdx.x] = sd[0];
}

// ---- row_ptr scan stage 2 ----
__global__ void scan2_kernel(const int* __restrict__ partial, int* __restrict__ base,
                             int* __restrict__ row_ptr) {
    __shared__ int ps[256];
    int t = threadIdx.x;
    int v = (t < SCAN_BLOCKS) ? partial[t] : 0;
    ps[t] = v;
    __syncthreads();
    for (int off = 1; off < 256; off <<= 1) {
        int add = (t >= off) ? ps[t - off] : 0;
        __syncthreads();
        ps[t] += add;
        __syncthreads();
    }
    if (t < SCAN_BLOCKS) base[t] = ps[t] - v;
    if (t == SCAN_BLOCKS - 1) row_ptr[N_NODES] = ps[t];
}

// ---- row_ptr scan stage 3 ----
__global__ void scan3_kernel(const int* __restrict__ deg, const int* __restrict__ base,
                             int* __restrict__ row_ptr) {
    int node = blockIdx.x * 256 + threadIdx.x;
    int t = threadIdx.x;
    int d = (node < N_NODES) ? deg[node] : 0;
    __shared__ int ps[256];
    ps[t] = d;
    __syncthreads();
    for (int off = 1; off < 256; off <<= 1) {
        int add = (t >= off) ? ps[t - off] : 0;
        __syncthreads();
        ps[t] += add;
        __syncthreads();
    }
    if (node < N_NODES) row_ptr[node] = base[blockIdx.x] + ps[t] - d;
}

// ---- per-block LDS degree histogram (TRANSPOSED out) + in-block rank ----
__global__ void bhist_kernel(const int* __restrict__ deg, int* __restrict__ bhistT,
                             int* __restrict__ rank) {
    __shared__ int lh[DMAX];
    const int t = threadIdx.x;
    if (t < DMAX) lh[t] = 0;
    __syncthreads();
    int n = blockIdx.x * 256 + t;
    if (n < N_NODES) {
        int b = min(deg[n], DMAX - 1);
        rank[n] = atomicAdd(&lh[b], 1);  // LDS atomic
    }
    __syncthreads();
    if (t < DMAX) bhistT[t * SCAN_BLOCKS + blockIdx.x] = lh[t];  // bucket-major
}

// ---- generic 3-stage exclusive scan over TS_N ints (bucket-major hist) ----
__global__ void gscan1_kernel(const int* __restrict__ in, int* __restrict__ partial) {
    int i = blockIdx.x * 256 + threadIdx.x;
    int v = (i < TS_N) ? in[i] : 0;
    __shared__ int sd[256];
    sd[threadIdx.x] = v;
    __syncthreads();
    for (int off = 128; off > 0; off >>= 1) {
        if (threadIdx.x < off) sd[threadIdx.x] += sd[threadIdx.x + off];
        __syncthreads();
    }
    if (threadIdx.x == 0) partial[blockIdx.x] = sd[0];
}
__global__ void gscan2_kernel(const int* __restrict__ partial, int* __restrict__ base) {
    __shared__ int ps[256];
    int t = threadIdx.x;
    int v = (t < TS_BLOCKS) ? partial[t] : 0;
    ps[t] = v;
    __syncthreads();
    for (int off = 1; off < 256; off <<= 1) {
        int add = (t >= off) ? ps[t - off] : 0;
        __syncthreads();
        ps[t] += add;
        __syncthreads();
    }
    if (t < TS_BLOCKS) base[t] = ps[t] - v;
}
__global__ void gscan3_kernel(const int* __restrict__ in, const int* __restrict__ base,
                              int* __restrict__ out) {
    int i = blockIdx.x * 256 + threadIdx.x;
    int t = threadIdx.x;
    int v = (i < TS_N) ? in[i] : 0;
    __shared__ int ps[256];
    ps[t] = v;
    __syncthreads();
    for (int off = 1; off < 256; off <<= 1) {
        int add = (t >= off) ? ps[t - off] : 0;
        __syncthreads();
        ps[t] += add;
        __syncthreads();
    }
    if (i < TS_N) out[i] = base[blockIdx.x] + ps[t] - v;  // exclusive
}

// ---- scatter nodes into ASCENDING-degree permutation (no global atomics) ----
__global__ void perm2_kernel(const int* __restrict__ deg, const int* __restrict__ rank,
                             const int* __restrict__ bbase2T, int* __restrict__ perm) {
    int n = blockIdx.x * 256 + threadIdx.x;
    if (n < N_NODES) {
        int b = min(deg[n], DMAX - 1);
        int pos = bbase2T[b * SCAN_BLOCKS + blockIdx.x] + rank[n];
        if (pos >= 0 && pos < N_NODES) perm[pos] = n;
    }
}

// ---- non-atomic scatter into packed CSR: csru[pos] = (fp16(w)<<16) | src ----
__global__ void build_csr_kernel(const int2* __restrict__ ei, const float* __restrict__ ew,
                                 const int* __restrict__ slot, const int* __restrict__ row_ptr,
                                 unsigned int* __restrict__ csru) {
    int e = blockIdx.x * blockDim.x + threadIdx.x;
    if (e >= N_EDGES) return;
    int2 sd = ei[e];
    int pos = row_ptr[sd.y] + slot[e];
    unsigned short wh = __half_as_ushort(__float2half(ew[e]));
    if (pos >= 0 && pos < N_EDGES)
        csru[pos] = (unsigned int)sd.x | ((unsigned int)wh << 16);  // src < 65536
}

// ---- fp16 transposed weights: WT16 (4 layers) then WTO16 (out proj) in one launch ----
__global__ void prep_w_kernel(const float* __restrict__ W_layers, const float* __restrict__ W_out,
                              _Float16* __restrict__ WT16, _Float16* __restrict__ WTO16) {
    int idx = blockIdx.x * 256 + threadIdx.x;
    if (idx < DEPTH * INT_F * INT_F) {
        int l = idx >> 14;
        int rem = idx & 16383;
        int n = rem >> 7;
        int k = rem & 127;
        WT16[idx] = (_Float16)W_layers[(size_t)l * 16384 + (size_t)k * 128 + n];
    } else {
        int j = idx - DEPTH * INT_F * INT_F;  // < 4096
        int n = j >> 7;
        int k = j & 127;
        WTO16[j] = (_Float16)W_out[(size_t)k * OUT_F + n];
    }
}

// ---- h16 = fp16(X @ W_in + b_in)  (16 nodes per 256-thread block) ----
__global__ void gemm_in_kernel(const float* __restrict__ X, const float* __restrict__ W,
                               const float* __restrict__ b, __half* __restrict__ h16) {
    __shared__ float xs[16][IN_F];
    const int base = blockIdx.x * 16;
    const int t = threadIdx.x;
    ((float4*)xs)[t] = ((const float4*)(X + (size_t)base * IN_F))[t];
    __syncthreads();
    const int f = t & (INT_F - 1);
    const int rg = t >> 7;
    float acc[8];
    const float bv = b[f];
#pragma unroll
    for (int j = 0; j < 8; ++j) acc[j] = bv;
#pragma unroll 4
    for (int k = 0; k < IN_F; ++k) {
        float w = W[k * INT_F + f];
#pragma unroll
        for (int j = 0; j < 8; ++j) acc[j] += xs[rg * 8 + j][k] * w;
    }
#pragma unroll
    for (int j = 0; j < 8; ++j)
        h16[(size_t)(base + rg * 8 + j) * INT_F + f] = __float2half(acc[j]);
}

// ---- fused layer (perm order): 256 thr = 4 waves = 16 nodes ----
template <bool LAST>
__global__ __launch_bounds__(256) void fused_layer_kernel(
    const int* __restrict__ row_ptr, const unsigned int* __restrict__ csru,
    const int* __restrict__ perm, const __half* h16_in, const _Float16* __restrict__ WT16,
    const float* __restrict__ b, __half* __restrict__ h16_out,
    const _Float16* __restrict__ WTO16, const float* __restrict__ b_out,
    float* __restrict__ h_fp32_out, float* __restrict__ out1) {
    __shared__ _Float16 as[16 * 136];  // 16 rows x 272B (128 halves + 8 pad)
    __shared__ int pnodes[16];
    const int t = threadIdx.x;         // 0..255
    const int row0 = blockIdx.x * 16;  // 3125 * 16 == 50000, exact

    if (t < 16) {
        int n = perm[row0 + t];
        pnodes[t] = (n >= 0 && n < N_NODES) ? n : 0;  // clamp: fault -> wrong answer
    }
    __syncthreads();

    // ---- phase 1: gather. 16 lanes/node; lane covers 8 features (1 uint4). ----
    const int nl = t >> 4;  // local node 0..15
    const int sl = t & 15;  // feature sixteenth
    const int node = pnodes[nl];
    const uint4* h16q = (const uint4*)h16_in;

    int s = row_ptr[node], e = row_ptr[node + 1];
    s = max(0, min(s, N_EDGES));   // clamp: fault -> wrong answer
    e = max(s, min(e, N_EDGES));
    __half2 acc2[4];
    const __half2 zero2 = __floats2half2_rn(0.f, 0.f);
#pragma unroll
    for (int q = 0; q < 4; ++q) acc2[q] = zero2;

    int i = s;
    for (; i + 3 < e; i += 4) {  // 4 independent row loads in flight
        unsigned int u0 = csru[i], u1 = csru[i + 1], u2 = csru[i + 2], u3 = csru[i + 3];
        uint4 r0 = h16q[(size_t)(u0 & 0xFFFFu) * 16 + sl];
        uint4 r1 = h16q[(size_t)(u1 & 0xFFFFu) * 16 + sl];
        uint4 r2 = h16q[(size_t)(u2 & 0xFFFFu) * 16 + sl];
        uint4 r3 = h16q[(size_t)(u3 & 0xFFFFu) * 16 + sl];
        __half2 w0 = __half2half2(__ushort_as_half((unsigned short)(u0 >> 16)));
        __half2 w1 = __half2half2(__ushort_as_half((unsigned short)(u1 >> 16)));
        __half2 w2 = __half2half2(__ushort_as_half((unsigned short)(u2 >> 16)));
        __half2 w3 = __half2half2(__ushort_as_half((unsigned short)(u3 >> 16)));
        const __half2* p0 = (const __half2*)&r0;
        const __half2* p1 = (const __half2*)&r1;
        const __half2* p2 = (const __half2*)&r2;
        const __half2* p3 = (const __half2*)&r3;
#pragma unroll
        for (int q = 0; q < 4; ++q) {
            acc2[q] = __hfma2(w0, p0[q], acc2[q]);
            acc2[q] = __hfma2(w1, p1[q], acc2[q]);
            acc2[q] = __hfma2(w2, p2[q], acc2[q]);
            acc2[q] = __hfma2(w3, p3[q], acc2[q]);
        }
    }
    for (; i < e; ++i) {
        unsigned int u0 = csru[i];
        uint4 r0 = h16q[(size_t)(u0 & 0xFFFFu) * 16 + sl];
        __half2 w0 = __half2half2(__ushort_as_half((unsigned short)(u0 >> 16)));
        const __half2* p0 = (const __half2*)&r0;
#pragma unroll
        for (int q = 0; q < 4; ++q) acc2[q] = __hfma2(w0, p0[q], acc2[q]);
    }
    const float inv = 1.0f / fmaxf((float)(e - s), 1.0f);

    // mean in fp32, stage to LDS
    {
        uint4 o;
        unsigned int* op = &o.x;
#pragma unroll
        for (int q = 0; q < 4; ++q) {
            float2 f = __half22float2(acc2[q]);
            __half2 hv = __floats2half2_rn(f.x * inv, f.y * inv);
            op[q] = *(const unsigned int*)&hv;
        }
        *(uint4*)(as + nl * 136 + sl * 8) = o;
    }
    __syncthreads();

    // ---- phase 2: MFMA. wave wv computes col-tiles [wv*2, wv*2+2). ----
    const int wv = t >> 6;
    const int lane = t & 63;
    const int r = lane & 15;
    const int ksel = lane >> 4;

    half8 afr[4];
#pragma unroll
    for (int ks = 0; ks < 4; ++ks)
        afr[ks] = *(const half8*)(as + r * 136 + ks * 32 + ksel * 8);

    floatx4 accd[2];
#pragma unroll
    for (int c4 = 0; c4 < 2; ++c4) accd[c4] = (floatx4){0.f, 0.f, 0.f, 0.f};

#pragma unroll
    for (int c4 = 0; c4 < 2; ++c4) {
        const int ct = wv * 2 + c4;
        const _Float16* wbase = WT16 + (size_t)(ct * 16 + r) * INT_F + ksel * 8;
        half8 b0 = *(const half8*)(wbase + 0);
        half8 b1 = *(const half8*)(wbase + 32);
        half8 b2 = *(const half8*)(wbase + 64);
        half8 b3 = *(const half8*)(wbase + 96);
        accd[c4] = __builtin_amdgcn_mfma_f32_16x16x32_f16(afr[0], b0, accd[c4], 0, 0, 0);
        accd[c4] = __builtin_amdgcn_mfma_f32_16x16x32_f16(afr[1], b1, accd[c4], 0, 0, 0);
        accd[c4] = __builtin_amdgcn_mfma_f32_16x16x32_f16(afr[2], b2, accd[c4], 0, 0, 0);
        accd[c4] = __builtin_amdgcn_mfma_f32_16x16x32_f16(afr[3], b3, accd[c4], 0, 0, 0);
    }

    // ---- phase 3a: bias + lrelu, write activation back to LDS (fp16) ----
    __syncthreads();
#pragma unroll
    for (int c4 = 0; c4 < 2; ++c4) {
        const int ct = wv * 2 + c4;
        const int col = ct * 16 + r;
        const float bias = b[col];
#pragma unroll
        for (int reg = 0; reg < 4; ++reg) {
            const int rowl = ksel * 4 + reg;
            float z = accd[c4][reg] + bias;
            float a = (z >= 0.f) ? z : NEG_SLOPE * z;
            as[rowl * 136 + col] = (_Float16)a;
        }
    }
    __syncthreads();

    // ---- phase 3b: coalesced residual; mid layers store h16_out, LAST stores fp32 h
    //      (h16_out write skipped in LAST: nothing reads it) ----
    {
        const int rowl = t >> 4;
        const int part = t & 15;
        const int row = pnodes[rowl];
        uint4 av = *(const uint4*)(as + rowl * 136 + part * 8);
        uint4 hv = h16q[(size_t)row * 16 + part];
        const __half2* ap = (const __half2*)&av;
        const __half2* hp = (const __half2*)&hv;
        uint4 o;
        unsigned int* op = &o.x;
        float nh[8];
#pragma unroll
        for (int q = 0; q < 4; ++q) {
            float2 fa = __half22float2(ap[q]);
            float2 fh = __half22float2(hp[q]);
            nh[2 * q + 0] = fh.x + fa.x;
            nh[2 * q + 1] = fh.y + fa.y;
            __half2 hv2 = __floats2half2_rn(nh[2 * q], nh[2 * q + 1]);
            op[q] = *(const unsigned int*)&hv2;
        }
        if (!LAST) {
            ((uint4*)h16_out)[(size_t)row * 16 + part] = o;
        } else {
            float4* f4 = (float4*)(h_fp32_out + (size_t)row * INT_F + part * 8);
            f4[0] = make_float4(nh[0], nh[1], nh[2], nh[3]);
            f4[1] = make_float4(nh[4], nh[5], nh[6], nh[7]);
            *(uint4*)(as + rowl * 136 + part * 8) = o;  // h_final for out-proj
        }
    }

    // ---- phase 4 (LAST only): out = h_final @ W_out + b_out via MFMA on waves 0-1 ----
    if (LAST) {
        __syncthreads();
        if (wv < 2) {
            half8 ofr[4];
#pragma unroll
            for (int ks = 0; ks < 4; ++ks)
                ofr[ks] = *(const half8*)(as + r * 136 + ks * 32 + ksel * 8);
            floatx4 acco = (floatx4){0.f, 0.f, 0.f, 0.f};
            const _Float16* wbase = WTO16 + (size_t)(wv * 16 + r) * INT_F + ksel * 8;
            half8 b0 = *(const half8*)(wbase + 0);
            half8 b1 = *(const half8*)(wbase + 32);
            half8 b2 = *(const half8*)(wbase + 64);
            half8 b3 = *(const half8*)(wbase + 96);
            acco = __builtin_amdgcn_mfma_f32_16x16x32_f16(ofr[0], b0, acco, 0, 0, 0);
            acco = __builtin_amdgcn_mfma_f32_16x16x32_f16(ofr[1], b1, acco, 0, 0, 0);
            acco = __builtin_amdgcn_mfma_f32_16x16x32_f16(ofr[2], b2, acco, 0, 0, 0);
            acco = __builtin_amdgcn_mfma_f32_16x16x32_f16(ofr[3], b3, acco, 0, 0, 0);
            const int col = wv * 16 + r;
            const float bias = b_out[col];
#pragma unroll
            for (int reg = 0; reg < 4; ++reg) {
                const int rowl = ksel * 4 + reg;
                const int row = pnodes[rowl];
                out1[(size_t)row * OUT_F + col] = acco[reg] + bias;
            }
        }
    }
}

extern "C" void kernel_launch(void* const* d_in, const int* in_sizes, int n_in,
                              void* d_out, int out_size, void* d_ws, size_t ws_size,
                              hipStream_t stream) {
    const float* X        = (const float*)d_in[0];
    const int2*  ei       = (const int2*)d_in[1];
    const float* ew       = (const float*)d_in[2];
    const float* W_in     = (const float*)d_in[3];
    const float* b_in     = (const float*)d_in[4];
    const float* W_layers = (const float*)d_in[5];
    const float* b_layers = (const float*)d_in[6];
    const float* W_out    = (const float*)d_in[7];
    const float* b_out    = (const float*)d_in[8];

    float* out1 = (float*)d_out;
    float* hf32 = out1 + (size_t)N_NODES * OUT_F;  // fp32 h output (written by last layer)

    // workspace layout (~32 MB); 16B alignment maintained
    char* ws = (char*)d_ws;
    __half*   h16A  = (__half*)ws;    ws += (size_t)N_NODES * INT_F * 2;        // 12.8 MB
    __half*   h16B  = (__half*)ws;    ws += (size_t)N_NODES * INT_F * 2;        // 12.8 MB
    _Float16* WT16  = (_Float16*)ws;  ws += (size_t)DEPTH * INT_F * INT_F * 2;  // 128 KB
    _Float16* WTO16 = (_Float16*)ws;  ws += (size_t)OUT_F * INT_F * 2;          // 8 KB
    unsigned int* csru = (unsigned int*)ws;  ws += (size_t)N_EDGES * 4;         // 2.5 MB
    int*  slot    = (int*)ws;   ws += (size_t)N_EDGES * 4;                      // 2.5 MB
    int*  row_ptr = (int*)ws;   ws += (size_t)(N_NODES + 1) * 4;
    int*  deg     = (int*)ws;   ws += (size_t)N_NODES * 4;
    int*  rank    = (int*)ws;   ws += (size_t)N_NODES * 4;
    int*  perm    = (int*)ws;   ws += (size_t)N_NODES * 4;
    int*  bhistT  = (int*)ws;   ws += (size_t)TS_N * 4;                         // 50 KB
    int*  bbase2T = (int*)ws;   ws += (size_t)TS_N * 4;                         // 50 KB
    int*  partial = (int*)ws;   ws += (size_t)SCAN_BLOCKS * 4;
    int*  bbase   = (int*)ws;   ws += (size_t)SCAN_BLOCKS * 4;
    int*  tpart   = (int*)ws;   ws += (size_t)TS_BLOCKS * 4;
    int*  tbase   = (int*)ws;   ws += (size_t)TS_BLOCKS * 4;

    // ---- build CSR + degree-sorted perm + fp16 weights (once per call) ----
    (void)hipMemsetAsync(deg, 0, (size_t)N_NODES * 4, stream);
    deg_slot_kernel<<<(N_EDGES + 255) / 256, 256, 0, stream>>>(ei, deg, slot);
    scan1_kernel<<<SCAN_BLOCKS, 256, 0, stream>>>(deg, partial);
    scan2_kernel<<<1, 256, 0, stream>>>(partial, bbase, row_ptr);
    scan3_kernel<<<SCAN_BLOCKS, 256, 0, stream>>>(deg, bbase, row_ptr);
    bhist_kernel<<<SCAN_BLOCKS, 256, 0, stream>>>(deg, bhistT, rank);
    gscan1_kernel<<<TS_BLOCKS, 256, 0, stream>>>(bhistT, tpart);
    gscan2_kernel<<<1, 256, 0, stream>>>(tpart, tbase);
    gscan3_kernel<<<TS_BLOCKS, 256, 0, stream>>>(bhistT, tbase, bbase2T);
    perm2_kernel<<<SCAN_BLOCKS, 256, 0, stream>>>(deg, rank, bbase2T, perm);
    build_csr_kernel<<<(N_EDGES + 255) / 256, 256, 0, stream>>>(ei, ew, slot, row_ptr, csru);
    prep_w_kernel<<<(DEPTH * INT_F * INT_F + OUT_F * INT_F) / 256, 256, 0, stream>>>(
        W_layers, W_out, WT16, WTO16);

    // ---- input projection (fp16 h) ----
    gemm_in_kernel<<<N_NODES / 16, 256, 0, stream>>>(X, W_in, b_in, h16A);

    // ---- fused layers: ping-pong; last layer writes fp32 h + out1 ----
    __half* hin = h16A;
    __half* hout = h16B;
    for (int i = 0; i < DEPTH - 1; ++i) {
        fused_layer_kernel<false><<<N_NODES / 16, 256, 0, stream>>>(
            row_ptr, csru, perm, hin, WT16 + (size_t)i * INT_F * INT_F,
            b_layers + (size_t)i * INT_F, hout, WTO16, b_out, nullptr, nullptr);
        __half* tmp = hin; hin = hout; hout = tmp;
    }
    fused_layer_kernel<true><<<N_NODES / 16, 256, 0, stream>>>(
        row_ptr, csru, perm, hin, WT16 + (size_t)(DEPTH - 1) * INT_F * INT_F,
        b_layers + (size_t)(DEPTH - 1) * INT_F, hout, WTO16, b_out, hf32, out1);
}

// Round 21
// 221.349 us; speedup vs baseline: 1.0656x; 1.0216x over previous
//
#include <hip/hip_runtime.h>
#include <hip/hip_fp16.h>

// Simple GNN: h = X@W_in+b; 4x { agg = segmean(w*h[src], dst); h += lrelu(agg@W_l+b_l) }
// out = (h@W_out+b_out, h)
// Round 21: prep-chain consolidation (bhist+scan1 merged; scan3+perm2 merged: 11 -> 9
//           launches, 2 fewer deg passes) + 8-edge-unrolled gather head loop.

#define N_NODES 50000
#define N_EDGES 625000
#define IN_F 64
#define INT_F 128
#define OUT_F 32
#define DEPTH 4
#define NEG_SLOPE 0.01f

#define SCAN_BLOCKS 196            // 196*256 = 50176 >= N_NODES
#define DMAX 64                    // degree buckets 0..63 (clamped)
#define TS_N (DMAX * SCAN_BLOCKS)  // 12544 transposed-hist elements
#define TS_BLOCKS ((TS_N + 255) / 256)  // 49

typedef _Float16 half8 __attribute__((ext_vector_type(8)));
typedef float floatx4 __attribute__((ext_vector_type(4)));

// ---- in-degree + slot ----
__global__ void deg_slot_kernel(const int2* __restrict__ ei, int* __restrict__ deg,
                                int* __restrict__ slot) {
    int i = blockIdx.x * blockDim.x + threadIdx.x;
    if (i < N_EDGES) slot[i] = atomicAdd(&deg[ei[i].y], 1);
}

// ---- merged: per-block deg sum (scan1) + LDS degree histogram + rank ----
__global__ void bhist_scan1_kernel(const int* __restrict__ deg, int* __restrict__ partial,
                                   int* __restrict__ bhistT, int* __restrict__ rank) {
    __shared__ int lh[DMAX];
    __shared__ int sd[256];
    const int t = threadIdx.x;
    if (t < DMAX) lh[t] = 0;
    __syncthreads();
    int n = blockIdx.x * 256 + t;
    int d = (n < N_NODES) ? deg[n] : 0;
    if (n < N_NODES) {
        int b = min(d, DMAX - 1);
        rank[n] = atomicAdd(&lh[b], 1);  // LDS atomic
    }
    sd[t] = d;
    __syncthreads();
    for (int off = 128; off > 0; off >>= 1) {
        if (t < off) sd[t] += sd[t + off];
        __syncthreads();
    }
    if (t == 0) partial[blockIdx.x] = sd[0];
    if (t < DMAX) bhistT[t * SCAN_BLOCKS + blockIdx.x] = lh[t];  // bucket-major
}

// ---- row_ptr scan stage 2 ----
__global__ void scan2_kernel(const int* __restrict__ partial, int* __restrict__ base,
                             int* __restrict__ row_ptr) {
    __shared__ int ps[256];
    int t = threadIdx.x;
    int v = (t < SCAN_BLOCKS) ? partial[t] : 0;
    ps[t] = v;
    __syncthreads();
    for (int off = 1; off < 256; off <<= 1) {
        int add = (t >= off) ? ps[t - off] : 0;
        __syncthreads();
        ps[t] += add;
        __syncthreads();
    }
    if (t < SCAN_BLOCKS) base[t] = ps[t] - v;
    if (t == SCAN_BLOCKS - 1) row_ptr[N_NODES] = ps[t];
}

// ---- generic 3-stage exclusive scan over TS_N ints (bucket-major hist) ----
__global__ void gscan1_kernel(const int* __restrict__ in, int* __restrict__ partial) {
    int i = blockIdx.x * 256 + threadIdx.x;
    int v = (i < TS_N) ? in[i] : 0;
    __shared__ int sd[256];
    sd[threadIdx.x] = v;
    __syncthreads();
    for (int off = 128; off > 0; off >>= 1) {
        if (threadIdx.x < off) sd[threadIdx.x] += sd[threadIdx.x + off];
        __syncthreads();
    }
    if (threadIdx.x == 0) partial[blockIdx.x] = sd[0];
}
__global__ void gscan2_kernel(const int* __restrict__ partial, int* __restrict__ base) {
    __shared__ int ps[256];
    int t = threadIdx.x;
    int v = (t < TS_BLOCKS) ? partial[t] : 0;
    ps[t] = v;
    __syncthreads();
    for (int off = 1; off < 256; off <<= 1) {
        int add = (t >= off) ? ps[t - off] : 0;
        __syncthreads();
        ps[t] += add;
        __syncthreads();
    }
    if (t < TS_BLOCKS) base[t] = ps[t] - v;
}
__global__ void gscan3_kernel(const int* __restrict__ in, const int* __restrict__ base,
                              int* __restrict__ out) {
    int i = blockIdx.x * 256 + threadIdx.x;
    int t = threadIdx.x;
    int v = (i < TS_N) ? in[i] : 0;
    __shared__ int ps[256];
    ps[t] = v;
    __syncthreads();
    for (int off = 1; off < 256; off <<= 1) {
        int add = (t >= off) ? ps[t - off] : 0;
        __syncthreads();
        ps[t] += add;
        __syncthreads();
    }
    if (i < TS_N) out[i] = base[blockIdx.x] + ps[t] - v;  // exclusive
}

// ---- merged: row_ptr stage 3 + ascending-degree perm scatter ----
__global__ void scan3_perm2_kernel(const int* __restrict__ deg, const int* __restrict__ base,
                                   const int* __restrict__ rank, const int* __restrict__ bbase2T,
                                   int* __restrict__ row_ptr, int* __restrict__ perm) {
    int node = blockIdx.x * 256 + threadIdx.x;
    int t = threadIdx.x;
    int d = (node < N_NODES) ? deg[node] : 0;
    __shared__ int ps[256];
    ps[t] = d;
    __syncthreads();
    for (int off = 1; off < 256; off <<= 1) {
        int add = (t >= off) ? ps[t - off] : 0;
        __syncthreads();
        ps[t] += add;
        __syncthreads();
    }
    if (node < N_NODES) {
        row_ptr[node] = base[blockIdx.x] + ps[t] - d;
        int b = min(d, DMAX - 1);
        int pos = bbase2T[b * SCAN_BLOCKS + blockIdx.x] + rank[node];
        if (pos >= 0 && pos < N_NODES) perm[pos] = node;
    }
}

// ---- non-atomic scatter into packed CSR: csru[pos] = (fp16(w)<<16) | src ----
__global__ void build_csr_kernel(const int2* __restrict__ ei, const float* __restrict__ ew,
                                 const int* __restrict__ slot, const int* __restrict__ row_ptr,
                                 unsigned int* __restrict__ csru) {
    int e = blockIdx.x * blockDim.x + threadIdx.x;
    if (e >= N_EDGES) return;
    int2 sd = ei[e];
    int pos = row_ptr[sd.y] + slot[e];
    unsigned short wh = __half_as_ushort(__float2half(ew[e]));
    if (pos >= 0 && pos < N_EDGES)
        csru[pos] = (unsigned int)sd.x | ((unsigned int)wh << 16);  // src < 65536
}

// ---- fp16 transposed weights: WT16 (4 layers) then WTO16 (out proj) in one launch ----
__global__ void prep_w_kernel(const float* __restrict__ W_layers, const float* __restrict__ W_out,
                              _Float16* __restrict__ WT16, _Float16* __restrict__ WTO16) {
    int idx = blockIdx.x * 256 + threadIdx.x;
    if (idx < DEPTH * INT_F * INT_F) {
        int l = idx >> 14;
        int rem = idx & 16383;
        int n = rem >> 7;
        int k = rem & 127;
        WT16[idx] = (_Float16)W_layers[(size_t)l * 16384 + (size_t)k * 128 + n];
    } else {
        int j = idx - DEPTH * INT_F * INT_F;  // < 4096
        int n = j >> 7;
        int k = j & 127;
        WTO16[j] = (_Float16)W_out[(size_t)k * OUT_F + n];
    }
}

// ---- h16 = fp16(X @ W_in + b_in)  (16 nodes per 256-thread block) ----
__global__ void gemm_in_kernel(const float* __restrict__ X, const float* __restrict__ W,
                               const float* __restrict__ b, __half* __restrict__ h16) {
    __shared__ float xs[16][IN_F];
    const int base = blockIdx.x * 16;
    const int t = threadIdx.x;
    ((float4*)xs)[t] = ((const float4*)(X + (size_t)base * IN_F))[t];
    __syncthreads();
    const int f = t & (INT_F - 1);
    const int rg = t >> 7;
    float acc[8];
    const float bv = b[f];
#pragma unroll
    for (int j = 0; j < 8; ++j) acc[j] = bv;
#pragma unroll 4
    for (int k = 0; k < IN_F; ++k) {
        float w = W[k * INT_F + f];
#pragma unroll
        for (int j = 0; j < 8; ++j) acc[j] += xs[rg * 8 + j][k] * w;
    }
#pragma unroll
    for (int j = 0; j < 8; ++j)
        h16[(size_t)(base + rg * 8 + j) * INT_F + f] = __float2half(acc[j]);
}

// ---- fused layer (perm order): 256 thr = 4 waves = 16 nodes ----
template <bool LAST>
__global__ __launch_bounds__(256) void fused_layer_kernel(
    const int* __restrict__ row_ptr, const unsigned int* __restrict__ csru,
    const int* __restrict__ perm, const __half* h16_in, const _Float16* __restrict__ WT16,
    const float* __restrict__ b, __half* __restrict__ h16_out,
    const _Float16* __restrict__ WTO16, const float* __restrict__ b_out,
    float* __restrict__ h_fp32_out, float* __restrict__ out1) {
    __shared__ _Float16 as[16 * 136];  // 16 rows x 272B (128 halves + 8 pad)
    __shared__ int pnodes[16];
    const int t = threadIdx.x;         // 0..255
    const int row0 = blockIdx.x * 16;  // 3125 * 16 == 50000, exact

    if (t < 16) {
        int n = perm[row0 + t];
        pnodes[t] = (n >= 0 && n < N_NODES) ? n : 0;  // clamp: fault -> wrong answer
    }
    __syncthreads();

    // ---- phase 1: gather. 16 lanes/node; lane covers 8 features (1 uint4). ----
    const int nl = t >> 4;  // local node 0..15
    const int sl = t & 15;  // feature sixteenth
    const int node = pnodes[nl];
    const uint4* h16q = (const uint4*)h16_in;

    int s = row_ptr[node], e = row_ptr[node + 1];
    s = max(0, min(s, N_EDGES));   // clamp: fault -> wrong answer
    e = max(s, min(e, N_EDGES));
    __half2 acc2[4];
    const __half2 zero2 = __floats2half2_rn(0.f, 0.f);
#pragma unroll
    for (int q = 0; q < 4; ++q) acc2[q] = zero2;

    int i = s;
    for (; i + 7 < e; i += 8) {  // 8 independent row loads in flight
        unsigned int u[8];
        uint4 rr[8];
#pragma unroll
        for (int j = 0; j < 8; ++j) u[j] = csru[i + j];
#pragma unroll
        for (int j = 0; j < 8; ++j) rr[j] = h16q[(size_t)(u[j] & 0xFFFFu) * 16 + sl];
#pragma unroll
        for (int j = 0; j < 8; ++j) {
            __half2 w = __half2half2(__ushort_as_half((unsigned short)(u[j] >> 16)));
            const __half2* p = (const __half2*)&rr[j];
#pragma unroll
            for (int q = 0; q < 4; ++q) acc2[q] = __hfma2(w, p[q], acc2[q]);
        }
    }
    for (; i + 3 < e; i += 4) {  // 4-edge tail
        unsigned int u0 = csru[i], u1 = csru[i + 1], u2 = csru[i + 2], u3 = csru[i + 3];
        uint4 r0 = h16q[(size_t)(u0 & 0xFFFFu) * 16 + sl];
        uint4 r1 = h16q[(size_t)(u1 & 0xFFFFu) * 16 + sl];
        uint4 r2 = h16q[(size_t)(u2 & 0xFFFFu) * 16 + sl];
        uint4 r3 = h16q[(size_t)(u3 & 0xFFFFu) * 16 + sl];
        __half2 w0 = __half2half2(__ushort_as_half((unsigned short)(u0 >> 16)));
        __half2 w1 = __half2half2(__ushort_as_half((unsigned short)(u1 >> 16)));
        __half2 w2 = __half2half2(__ushort_as_half((unsigned short)(u2 >> 16)));
        __half2 w3 = __half2half2(__ushort_as_half((unsigned short)(u3 >> 16)));
        const __half2* p0 = (const __half2*)&r0;
        const __half2* p1 = (const __half2*)&r1;
        const __half2* p2 = (const __half2*)&r2;
        const __half2* p3 = (const __half2*)&r3;
#pragma unroll
        for (int q = 0; q < 4; ++q) {
            acc2[q] = __hfma2(w0, p0[q], acc2[q]);
            acc2[q] = __hfma2(w1, p1[q], acc2[q]);
            acc2[q] = __hfma2(w2, p2[q], acc2[q]);
            acc2[q] = __hfma2(w3, p3[q], acc2[q]);
        }
    }
    for (; i < e; ++i) {
        unsigned int u0 = csru[i];
        uint4 r0 = h16q[(size_t)(u0 & 0xFFFFu) * 16 + sl];
        __half2 w0 = __half2half2(__ushort_as_half((unsigned short)(u0 >> 16)));
        const __half2* p0 = (const __half2*)&r0;
#pragma unroll
        for (int q = 0; q < 4; ++q) acc2[q] = __hfma2(w0, p0[q], acc2[q]);
    }
    const float inv = 1.0f / fmaxf((float)(e - s), 1.0f);

    // mean in fp32, stage to LDS
    {
        uint4 o;
        unsigned int* op = &o.x;
#pragma unroll
        for (int q = 0; q < 4; ++q) {
            float2 f = __half22float2(acc2[q]);
            __half2 hv = __floats2half2_rn(f.x * inv, f.y * inv);
            op[q] = *(const unsigned int*)&hv;
        }
        *(uint4*)(as + nl * 136 + sl * 8) = o;
    }
    __syncthreads();

    // ---- phase 2: MFMA. wave wv computes col-tiles [wv*2, wv*2+2). ----
    const int wv = t >> 6;
    const int lane = t & 63;
    const int r = lane & 15;
    const int ksel = lane >> 4;

    half8 afr[4];
#pragma unroll
    for (int ks = 0; ks < 4; ++ks)
        afr[ks] = *(const half8*)(as + r * 136 + ks * 32 + ksel * 8);

    floatx4 accd[2];
#pragma unroll
    for (int c4 = 0; c4 < 2; ++c4) accd[c4] = (floatx4){0.f, 0.f, 0.f, 0.f};

#pragma unroll
    for (int c4 = 0; c4 < 2; ++c4) {
        const int ct = wv * 2 + c4;
        const _Float16* wbase = WT16 + (size_t)(ct * 16 + r) * INT_F + ksel * 8;
        half8 b0 = *(const half8*)(wbase + 0);
        half8 b1 = *(const half8*)(wbase + 32);
        half8 b2 = *(const half8*)(wbase + 64);
        half8 b3 = *(const half8*)(wbase + 96);
        accd[c4] = __builtin_amdgcn_mfma_f32_16x16x32_f16(afr[0], b0, accd[c4], 0, 0, 0);
        accd[c4] = __builtin_amdgcn_mfma_f32_16x16x32_f16(afr[1], b1, accd[c4], 0, 0, 0);
        accd[c4] = __builtin_amdgcn_mfma_f32_16x16x32_f16(afr[2], b2, accd[c4], 0, 0, 0);
        accd[c4] = __builtin_amdgcn_mfma_f32_16x16x32_f16(afr[3], b3, accd[c4], 0, 0, 0);
    }

    // ---- phase 3a: bias + lrelu, write activation back to LDS (fp16) ----
    __syncthreads();
#pragma unroll
    for (int c4 = 0; c4 < 2; ++c4) {
        const int ct = wv * 2 + c4;
        const int col = ct * 16 + r;
        const float bias = b[col];
#pragma unroll
        for (int reg = 0; reg < 4; ++reg) {
            const int rowl = ksel * 4 + reg;
            float z = accd[c4][reg] + bias;
            float a = (z >= 0.f) ? z : NEG_SLOPE * z;
            as[rowl * 136 + col] = (_Float16)a;
        }
    }
    __syncthreads();

    // ---- phase 3b: coalesced residual; mid layers store h16_out, LAST stores fp32 h ----
    {
        const int rowl = t >> 4;
        const int part = t & 15;
        const int row = pnodes[rowl];
        uint4 av = *(const uint4*)(as + rowl * 136 + part * 8);
        uint4 hv = h16q[(size_t)row * 16 + part];
        const __half2* ap = (const __half2*)&av;
        const __half2* hp = (const __half2*)&hv;
        uint4 o;
        unsigned int* op = &o.x;
        float nh[8];
#pragma unroll
        for (int q = 0; q < 4; ++q) {
            float2 fa = __half22float2(ap[q]);
            float2 fh = __half22float2(hp[q]);
            nh[2 * q + 0] = fh.x + fa.x;
            nh[2 * q + 1] = fh.y + fa.y;
            __half2 hv2 = __floats2half2_rn(nh[2 * q], nh[2 * q + 1]);
            op[q] = *(const unsigned int*)&hv2;
        }
        if (!LAST) {
            ((uint4*)h16_out)[(size_t)row * 16 + part] = o;
        } else {
            float4* f4 = (float4*)(h_fp32_out + (size_t)row * INT_F + part * 8);
            f4[0] = make_float4(nh[0], nh[1], nh[2], nh[3]);
            f4[1] = make_float4(nh[4], nh[5], nh[6], nh[7]);
            *(uint4*)(as + rowl * 136 + part * 8) = o;  // h_final for out-proj
        }
    }

    // ---- phase 4 (LAST only): out = h_final @ W_out + b_out via MFMA on waves 0-1 ----
    if (LAST) {
        __syncthreads();
        if (wv < 2) {
            half8 ofr[4];
#pragma unroll
            for (int ks = 0; ks < 4; ++ks)
                ofr[ks] = *(const half8*)(as + r * 136 + ks * 32 + ksel * 8);
            floatx4 acco = (floatx4){0.f, 0.f, 0.f, 0.f};
            const _Float16* wbase = WTO16 + (size_t)(wv * 16 + r) * INT_F + ksel * 8;
            half8 b0 = *(const half8*)(wbase + 0);
            half8 b1 = *(const half8*)(wbase + 32);
            half8 b2 = *(const half8*)(wbase + 64);
            half8 b3 = *(const half8*)(wbase + 96);
            acco = __builtin_amdgcn_mfma_f32_16x16x32_f16(ofr[0], b0, acco, 0, 0, 0);
            acco = __builtin_amdgcn_mfma_f32_16x16x32_f16(ofr[1], b1, acco, 0, 0, 0);
            acco = __builtin_amdgcn_mfma_f32_16x16x32_f16(ofr[2], b2, acco, 0, 0, 0);
            acco = __builtin_amdgcn_mfma_f32_16x16x32_f16(ofr[3], b3, acco, 0, 0, 0);
            const int col = wv * 16 + r;
            const float bias = b_out[col];
#pragma unroll
            for (int reg = 0; reg < 4; ++reg) {
                const int rowl = ksel * 4 + reg;
                const int row = pnodes[rowl];
                out1[(size_t)row * OUT_F + col] = acco[reg] + bias;
            }
        }
    }
}

extern "C" void kernel_launch(void* const* d_in, const int* in_sizes, int n_in,
                              void* d_out, int out_size, void* d_ws, size_t ws_size,
                              hipStream_t stream) {
    const float* X        = (const float*)d_in[0];
    const int2*  ei       = (const int2*)d_in[1];
    const float* ew       = (const float*)d_in[2];
    const float* W_in     = (const float*)d_in[3];
    const float* b_in     = (const float*)d_in[4];
    const float* W_layers = (const float*)d_in[5];
    const float* b_layers = (const float*)d_in[6];
    const float* W_out    = (const float*)d_in[7];
    const float* b_out    = (const float*)d_in[8];

    float* out1 = (float*)d_out;
    float* hf32 = out1 + (size_t)N_NODES * OUT_F;  // fp32 h output (written by last layer)

    // workspace layout (~32 MB); 16B alignment maintained
    char* ws = (char*)d_ws;
    __half*   h16A  = (__half*)ws;    ws += (size_t)N_NODES * INT_F * 2;        // 12.8 MB
    __half*   h16B  = (__half*)ws;    ws += (size_t)N_NODES * INT_F * 2;        // 12.8 MB
    _Float16* WT16  = (_Float16*)ws;  ws += (size_t)DEPTH * INT_F * INT_F * 2;  // 128 KB
    _Float16* WTO16 = (_Float16*)ws;  ws += (size_t)OUT_F * INT_F * 2;          // 8 KB
    unsigned int* csru = (unsigned int*)ws;  ws += (size_t)N_EDGES * 4;         // 2.5 MB
    int*  slot    = (int*)ws;   ws += (size_t)N_EDGES * 4;                      // 2.5 MB
    int*  row_ptr = (int*)ws;   ws += (size_t)(N_NODES + 1) * 4;
    int*  deg     = (int*)ws;   ws += (size_t)N_NODES * 4;
    int*  rank    = (int*)ws;   ws += (size_t)N_NODES * 4;
    int*  perm    = (int*)ws;   ws += (size_t)N_NODES * 4;
    int*  bhistT  = (int*)ws;   ws += (size_t)TS_N * 4;                         // 50 KB
    int*  bbase2T = (int*)ws;   ws += (size_t)TS_N * 4;                         // 50 KB
    int*  partial = (int*)ws;   ws += (size_t)SCAN_BLOCKS * 4;
    int*  bbase   = (int*)ws;   ws += (size_t)SCAN_BLOCKS * 4;
    int*  tpart   = (int*)ws;   ws += (size_t)TS_BLOCKS * 4;
    int*  tbase   = (int*)ws;   ws += (size_t)TS_BLOCKS * 4;

    // ---- build CSR + degree-sorted perm + fp16 weights (once per call) ----
    (void)hipMemsetAsync(deg, 0, (size_t)N_NODES * 4, stream);
    deg_slot_kernel<<<(N_EDGES + 255) / 256, 256, 0, stream>>>(ei, deg, slot);
    bhist_scan1_kernel<<<SCAN_BLOCKS, 256, 0, stream>>>(deg, partial, bhistT, rank);
    scan2_kernel<<<1, 256, 0, stream>>>(partial, bbase, row_ptr);
    gscan1_kernel<<<TS_BLOCKS, 256, 0, stream>>>(bhistT, tpart);
    gscan2_kernel<<<1, 256, 0, stream>>>(tpart, tbase);
    gscan3_kernel<<<TS_BLOCKS, 256, 0, stream>>>(bhistT, tbase, bbase2T);
    scan3_perm2_kernel<<<SCAN_BLOCKS, 256, 0, stream>>>(deg, bbase, rank, bbase2T, row_ptr, perm);
    build_csr_kernel<<<(N_EDGES + 255) / 256, 256, 0, stream>>>(ei, ew, slot, row_ptr, csru);
    prep_w_kernel<<<(DEPTH * INT_F * INT_F + OUT_F * INT_F) / 256, 256, 0, stream>>>(
        W_layers, W_out, WT16, WTO16);

    // ---- input projection (fp16 h) ----
    gemm_in_kernel<<<N_NODES / 16, 256, 0, stream>>>(X, W_in, b_in, h16A);

    // ---- fused layers: ping-pong; last layer writes fp32 h + out1 ----
    __half* hin = h16A;
    __half* hout = h16B;
    for (int i = 0; i < DEPTH - 1; ++i) {
        fused_layer_kernel<false><<<N_NODES / 16, 256, 0, stream>>>(
            row_ptr, csru, perm, hin, WT16 + (size_t)i * INT_F * INT_F,
            b_layers + (size_t)i * INT_F, hout, WTO16, b_out, nullptr, nullptr);
        __half* tmp = hin; hin = hout; hout = tmp;
    }
    fused_layer_kernel<true><<<N_NODES / 16, 256, 0, stream>>>(
        row_ptr, csru, perm, hin, WT16 + (size_t)(DEPTH - 1) * INT_F * INT_F,
        b_layers + (size_t)(DEPTH - 1) * INT_F, hout, WTO16, b_out, hf32, out1);
}